// Round 1
// baseline (382.935 us; speedup 1.0000x reference)
//
#include <hip/hip_runtime.h>
#include <hip/hip_bf16.h>

typedef __attribute__((ext_vector_type(8))) short short8;
typedef __attribute__((ext_vector_type(4))) float f32x4;
typedef __attribute__((ext_vector_type(4))) float f4v;
typedef __attribute__((ext_vector_type(4))) int   i4v;

#define SEQ 4096
#define NBH 16   // B*H

__device__ __forceinline__ short f2bf(float f) {
  union { float f; unsigned u; } x; x.f = f;
  unsigned r = x.u + 0x7FFFu + ((x.u >> 16) & 1u);
  return (short)(r >> 16);
}

__device__ __forceinline__ short8 cvt8(const float* __restrict__ src) {
  f4v v0 = *(const f4v*)src;
  f4v v1 = *(const f4v*)(src + 4);
  short8 r;
  r[0] = f2bf(v0[0]); r[1] = f2bf(v0[1]); r[2] = f2bf(v0[2]); r[3] = f2bf(v0[3]);
  r[4] = f2bf(v1[0]); r[5] = f2bf(v1[1]); r[6] = f2bf(v1[2]); r[7] = f2bf(v1[3]);
  return r;
}

// C[M,N] = A[M,K] * W[N,K]^T + bias.  M=8192, N=K=512.
// MODE 0: A fp32 (q) -> Qh bf16 [BH][SEQ][64], scaled by 0.125
// MODE 1: A fp32 (k) -> Kh bf16 [BH][SEQ][64]
// MODE 2: A fp32 (v) -> Vt bf16 [BH][64][SEQ]  (transposed store)
// MODE 3: A bf16 (ctx) -> out fp32 [M][512]
template <int MODE>
__global__ __launch_bounds__(256) void gemm_bt(
    const float* __restrict__ Af, const short* __restrict__ Ab,
    const float* __restrict__ W, const float* __restrict__ bias,
    void* __restrict__ Cout)
{
  __shared__ short As[128][72];
  __shared__ short Bs[64][72];
  const int t    = threadIdx.x;
  const int lane = t & 63;
  const int w    = t >> 6;
  const int wr   = w >> 1, wc = w & 1;
  const int tile_n = blockIdx.x * 64;
  const int tile_m = blockIdx.y * 128;

  f32x4 acc[4][2];
#pragma unroll
  for (int mi = 0; mi < 4; ++mi)
#pragma unroll
    for (int ni = 0; ni < 2; ++ni)
#pragma unroll
      for (int j = 0; j < 4; ++j) acc[mi][ni][j] = 0.f;

  for (int k0 = 0; k0 < 512; k0 += 64) {
    __syncthreads();
    if (MODE != 3) {
#pragma unroll
      for (int it = 0; it < 4; ++it) {
        int i = it * 256 + t;
        int r = i >> 3, sg = i & 7;
        *(short8*)&As[r][sg * 8] =
            cvt8(Af + (size_t)(tile_m + r) * 512 + k0 + sg * 8);
      }
    } else {
#pragma unroll
      for (int it = 0; it < 4; ++it) {
        int i = it * 256 + t;
        int r = i >> 3, sg = i & 7;
        *(short8*)&As[r][sg * 8] =
            *(const short8*)(Ab + (size_t)(tile_m + r) * 512 + k0 + sg * 8);
      }
    }
#pragma unroll
    for (int it = 0; it < 2; ++it) {
      int i = it * 256 + t;
      int r = i >> 3, sg = i & 7;
      *(short8*)&Bs[r][sg * 8] =
          cvt8(W + (size_t)(tile_n + r) * 512 + k0 + sg * 8);
    }
    __syncthreads();
#pragma unroll
    for (int kk = 0; kk < 2; ++kk) {
      short8 af[4], bfv[2];
#pragma unroll
      for (int mi = 0; mi < 4; ++mi)
        af[mi] = *(const short8*)&As[wr * 64 + mi * 16 + (lane & 15)][kk * 32 + (lane >> 4) * 8];
#pragma unroll
      for (int ni = 0; ni < 2; ++ni)
        bfv[ni] = *(const short8*)&Bs[wc * 32 + ni * 16 + (lane & 15)][kk * 32 + (lane >> 4) * 8];
#pragma unroll
      for (int mi = 0; mi < 4; ++mi)
#pragma unroll
        for (int ni = 0; ni < 2; ++ni)
          acc[mi][ni] = __builtin_amdgcn_mfma_f32_16x16x32_bf16(af[mi], bfv[ni], acc[mi][ni], 0, 0, 0);
    }
  }

#pragma unroll
  for (int mi = 0; mi < 4; ++mi) {
#pragma unroll
    for (int ni = 0; ni < 2; ++ni) {
#pragma unroll
      for (int j = 0; j < 4; ++j) {
        int m = tile_m + wr * 64 + mi * 16 + (lane >> 4) * 4 + j;
        int e = tile_n + wc * 32 + ni * 16 + (lane & 15);
        float val = acc[mi][ni][j] + bias[e];
        if (MODE == 0) val *= 0.125f;
        if (MODE == 3) {
          ((float*)Cout)[(size_t)m * 512 + e] = val;
        } else {
          int b = m >> 12, s = m & 4095;
          int h = e >> 6, d = e & 63;
          short* C = (short*)Cout;
          if (MODE == 2) {
            C[(size_t)((b * 8 + h) * 64 + d) * SEQ + s] = f2bf(val);
          } else {
            C[((size_t)(b * 8 + h) * SEQ + s) * 64 + d] = f2bf(val);
          }
        }
      }
    }
  }
}

// Flash attention. grid = (SEQ/128, NBH), block = 256 (4 waves x 32 q-rows).
// Qh pre-scaled by 1/sqrt(dh). Output ctx bf16 in concat layout [B*S][512].
__global__ __launch_bounds__(256) void attn_kernel(
    const short* __restrict__ Qh, const short* __restrict__ Kh,
    const short* __restrict__ Vt, short* __restrict__ ctx)
{
  __shared__ short Ks[64][72];
  __shared__ short Vs[64][72];
  __shared__ short Ps[4][32][72];
  const int t    = threadIdx.x;
  const int lane = t & 63;
  const int w    = t >> 6;
  const int bh   = blockIdx.y;
  const int q0   = blockIdx.x * 128 + w * 32;
  const size_t kvq   = (size_t)bh * SEQ * 64;
  const size_t vbase = (size_t)bh * 64 * SEQ;

  short8 qf[2][2];
#pragma unroll
  for (int mi = 0; mi < 2; ++mi)
#pragma unroll
    for (int kf = 0; kf < 2; ++kf)
      qf[mi][kf] = *(const short8*)(Qh + kvq + (size_t)(q0 + mi * 16 + (lane & 15)) * 64 + kf * 32 + (lane >> 4) * 8);

  f32x4 acc[2][4];
  float mrun[2][4], lrun[2][4];
#pragma unroll
  for (int mi = 0; mi < 2; ++mi)
#pragma unroll
    for (int j = 0; j < 4; ++j) {
      mrun[mi][j] = -1e30f;
      lrun[mi][j] = 0.f;
#pragma unroll
      for (int nb = 0; nb < 4; ++nb) acc[mi][nb][j] = 0.f;
    }

  for (int kt = 0; kt < SEQ / 64; ++kt) {
    __syncthreads();
#pragma unroll
    for (int it = 0; it < 2; ++it) {
      int i = it * 256 + t;
      int r = i >> 3, sg = i & 7;
      *(i4v*)&Ks[r][sg * 8] = *(const i4v*)(Kh + kvq + (size_t)(kt * 64 + r) * 64 + sg * 8);
      *(i4v*)&Vs[r][sg * 8] = *(const i4v*)(Vt + vbase + (size_t)r * SEQ + kt * 64 + sg * 8);
    }
    __syncthreads();

    f32x4 sc[2][4];
#pragma unroll
    for (int mi = 0; mi < 2; ++mi)
#pragma unroll
      for (int n = 0; n < 4; ++n)
#pragma unroll
        for (int j = 0; j < 4; ++j) sc[mi][n][j] = 0.f;

#pragma unroll
    for (int kf = 0; kf < 2; ++kf) {
      short8 kfr[4];
#pragma unroll
      for (int n = 0; n < 4; ++n)
        kfr[n] = *(const short8*)&Ks[n * 16 + (lane & 15)][kf * 32 + (lane >> 4) * 8];
#pragma unroll
      for (int mi = 0; mi < 2; ++mi)
#pragma unroll
        for (int n = 0; n < 4; ++n)
          sc[mi][n] = __builtin_amdgcn_mfma_f32_16x16x32_bf16(qf[mi][kf], kfr[n], sc[mi][n], 0, 0, 0);
    }

    // online softmax (scores already scaled via Q)
#pragma unroll
    for (int mi = 0; mi < 2; ++mi) {
      float tm[4], corr[4], rs[4];
#pragma unroll
      for (int j = 0; j < 4; ++j)
        tm[j] = fmaxf(fmaxf(sc[mi][0][j], sc[mi][1][j]), fmaxf(sc[mi][2][j], sc[mi][3][j]));
#pragma unroll
      for (int off = 1; off <= 8; off <<= 1)
#pragma unroll
        for (int j = 0; j < 4; ++j)
          tm[j] = fmaxf(tm[j], __shfl_xor(tm[j], off));
#pragma unroll
      for (int j = 0; j < 4; ++j) {
        float mn = fmaxf(mrun[mi][j], tm[j]);
        corr[j] = __expf(mrun[mi][j] - mn);
        mrun[mi][j] = mn;
        float r = 0.f;
#pragma unroll
        for (int n = 0; n < 4; ++n) {
          float p = __expf(sc[mi][n][j] - mn);
          sc[mi][n][j] = p;
          r += p;
        }
        rs[j] = r;
      }
#pragma unroll
      for (int off = 1; off <= 8; off <<= 1)
#pragma unroll
        for (int j = 0; j < 4; ++j)
          rs[j] += __shfl_xor(rs[j], off);
#pragma unroll
      for (int j = 0; j < 4; ++j)
        lrun[mi][j] = lrun[mi][j] * corr[j] + rs[j];
#pragma unroll
      for (int nb = 0; nb < 4; ++nb)
#pragma unroll
        for (int j = 0; j < 4; ++j) acc[mi][nb][j] *= corr[j];
#pragma unroll
      for (int n = 0; n < 4; ++n)
#pragma unroll
        for (int j = 0; j < 4; ++j)
          Ps[w][mi * 16 + (lane >> 4) * 4 + j][n * 16 + (lane & 15)] = f2bf(sc[mi][n][j]);
    }

    // PV
#pragma unroll
    for (int tf = 0; tf < 2; ++tf) {
      short8 pf[2], vf[4];
#pragma unroll
      for (int mi = 0; mi < 2; ++mi)
        pf[mi] = *(const short8*)&Ps[w][mi * 16 + (lane & 15)][tf * 32 + (lane >> 4) * 8];
#pragma unroll
      for (int nb = 0; nb < 4; ++nb)
        vf[nb] = *(const short8*)&Vs[nb * 16 + (lane & 15)][tf * 32 + (lane >> 4) * 8];
#pragma unroll
      for (int mi = 0; mi < 2; ++mi)
#pragma unroll
        for (int nb = 0; nb < 4; ++nb)
          acc[mi][nb] = __builtin_amdgcn_mfma_f32_16x16x32_bf16(pf[mi], vf[nb], acc[mi][nb], 0, 0, 0);
    }
  }

  const int b = bh >> 3, h = bh & 7;
#pragma unroll
  for (int mi = 0; mi < 2; ++mi)
#pragma unroll
    for (int j = 0; j < 4; ++j) {
      float inv = 1.0f / lrun[mi][j];
      int s = q0 + mi * 16 + (lane >> 4) * 4 + j;
      size_t row = (size_t)(b * SEQ + s);
#pragma unroll
      for (int nb = 0; nb < 4; ++nb) {
        int col = h * 64 + nb * 16 + (lane & 15);
        ctx[row * 512 + col] = f2bf(acc[mi][nb][j] * inv);
      }
    }
}

extern "C" void kernel_launch(void* const* d_in, const int* in_sizes, int n_in,
                              void* d_out, int out_size, void* d_ws, size_t ws_size,
                              hipStream_t stream) {
  const float* q  = (const float*)d_in[0];
  const float* k  = (const float*)d_in[1];
  const float* v  = (const float*)d_in[2];
  const float* Wq = (const float*)d_in[3];
  const float* bq = (const float*)d_in[4];
  const float* Wk = (const float*)d_in[5];
  const float* bk = (const float*)d_in[6];
  const float* Wv = (const float*)d_in[7];
  const float* bv = (const float*)d_in[8];
  const float* Wo = (const float*)d_in[9];
  const float* bo = (const float*)d_in[10];

  const size_t NELT = (size_t)NBH * SEQ * 64;  // 4,194,304
  short* Qh  = (short*)d_ws;
  short* Kh  = Qh + NELT;
  short* Vt  = Kh + NELT;
  short* ctx = Vt + NELT;

  dim3 gb(8, 64), tb(256);
  gemm_bt<0><<<gb, tb, 0, stream>>>(q, nullptr, Wq, bq, (void*)Qh);
  gemm_bt<1><<<gb, tb, 0, stream>>>(k, nullptr, Wk, bk, (void*)Kh);
  gemm_bt<2><<<gb, tb, 0, stream>>>(v, nullptr, Wv, bv, (void*)Vt);
  attn_kernel<<<dim3(SEQ / 128, NBH), tb, 0, stream>>>(Qh, Kh, Vt, ctx);
  gemm_bt<3><<<gb, tb, 0, stream>>>(nullptr, ctx, Wo, bo, d_out);
}

// Round 2
// 249.776 us; speedup vs baseline: 1.5331x; 1.5331x over previous
//
#include <hip/hip_runtime.h>
#include <hip/hip_bf16.h>

typedef __attribute__((ext_vector_type(8))) short short8;
typedef __attribute__((ext_vector_type(4))) float f32x4;
typedef __attribute__((ext_vector_type(4))) float f4v;
typedef __attribute__((ext_vector_type(4))) int   i4v;

#define SEQ 4096
#define NBH 16   // B*H
// 1/sqrt(64) * log2(e): attention computed in exp2 domain
#define SCALE_Q 0.18033688011112042f

__device__ __forceinline__ short f2bf(float f) {
  union { float f; unsigned u; } x; x.f = f;
  unsigned r = x.u + 0x7FFFu + ((x.u >> 16) & 1u);
  return (short)(r >> 16);
}

__device__ __forceinline__ unsigned cvt_pk_bf16(float lo, float hi) {
  unsigned r;
  asm("v_cvt_pk_bf16_f32 %0, %1, %2" : "=v"(r) : "v"(lo), "v"(hi));
  return r;
}

__device__ __forceinline__ short8 cvt8(const float* __restrict__ src) {
  f4v v0 = *(const f4v*)src;
  f4v v1 = *(const f4v*)(src + 4);
  union { unsigned u[4]; short8 s; } r;
  r.u[0] = cvt_pk_bf16(v0[0], v0[1]);
  r.u[1] = cvt_pk_bf16(v0[2], v0[3]);
  r.u[2] = cvt_pk_bf16(v1[0], v1[1]);
  r.u[3] = cvt_pk_bf16(v1[2], v1[3]);
  return r.s;
}

// C[M,N] = A[M,K] * W[N,K]^T + bias.  M=8192, N=K=512.
// Tile: BM=64, BN=128, BK=64. grid=(128 m-tiles, 4 n-tiles), 4 waves (1x4 over N).
// MODE 0: A fp32 (q) -> Qh bf16 [BH][SEQ][64], scaled by SCALE_Q
// MODE 1: A fp32 (k) -> Kh bf16 [BH][SEQ][64]
// MODE 2: A fp32 (v) -> Vt bf16 [BH][64][SEQ]  (transposed store)
// MODE 3: A bf16 (ctx) -> out fp32 [M][512]
template <int MODE>
__global__ __launch_bounds__(256) void gemm_bt(
    const float* __restrict__ Af, const short* __restrict__ Ab,
    const float* __restrict__ W, const float* __restrict__ bias,
    void* __restrict__ Cout)
{
  __shared__ short As[64][72];
  __shared__ short Bs[128][72];
  const int t    = threadIdx.x;
  const int lane = t & 63;
  const int w    = t >> 6;
  const int g    = lane >> 4;
  const int q    = lane & 15;
  const int tile_m = blockIdx.x * 64;
  const int tile_n = blockIdx.y * 128;

  f32x4 acc[4][2];
#pragma unroll
  for (int mi = 0; mi < 4; ++mi)
#pragma unroll
    for (int ni = 0; ni < 2; ++ni)
#pragma unroll
      for (int j = 0; j < 4; ++j) acc[mi][ni][j] = 0.f;

  for (int k0 = 0; k0 < 512; k0 += 64) {
    __syncthreads();
    if (MODE != 3) {
#pragma unroll
      for (int it = 0; it < 2; ++it) {
        int i = it * 256 + t;
        int r = i >> 3, sg = i & 7;
        *(short8*)&As[r][sg * 8] =
            cvt8(Af + (size_t)(tile_m + r) * 512 + k0 + sg * 8);
      }
    } else {
#pragma unroll
      for (int it = 0; it < 2; ++it) {
        int i = it * 256 + t;
        int r = i >> 3, sg = i & 7;
        *(short8*)&As[r][sg * 8] =
            *(const short8*)(Ab + (size_t)(tile_m + r) * 512 + k0 + sg * 8);
      }
    }
#pragma unroll
    for (int it = 0; it < 4; ++it) {
      int i = it * 256 + t;
      int r = i >> 3, sg = i & 7;
      *(short8*)&Bs[r][sg * 8] =
          cvt8(W + (size_t)(tile_n + r) * 512 + k0 + sg * 8);
    }
    __syncthreads();
#pragma unroll
    for (int kk = 0; kk < 2; ++kk) {
      short8 af[4], bfv[2];
#pragma unroll
      for (int mi = 0; mi < 4; ++mi)
        af[mi] = *(const short8*)&As[mi * 16 + q][kk * 32 + g * 8];
#pragma unroll
      for (int ni = 0; ni < 2; ++ni)
        bfv[ni] = *(const short8*)&Bs[w * 32 + ni * 16 + q][kk * 32 + g * 8];
#pragma unroll
      for (int mi = 0; mi < 4; ++mi)
#pragma unroll
        for (int ni = 0; ni < 2; ++ni)
          acc[mi][ni] = __builtin_amdgcn_mfma_f32_16x16x32_bf16(af[mi], bfv[ni], acc[mi][ni], 0, 0, 0);
    }
  }

#pragma unroll
  for (int mi = 0; mi < 4; ++mi) {
#pragma unroll
    for (int ni = 0; ni < 2; ++ni) {
#pragma unroll
      for (int j = 0; j < 4; ++j) {
        int m = tile_m + mi * 16 + g * 4 + j;
        int e = tile_n + w * 32 + ni * 16 + q;
        float val = acc[mi][ni][j] + bias[e];
        if (MODE == 0) val *= SCALE_Q;
        if (MODE == 3) {
          ((float*)Cout)[(size_t)m * 512 + e] = val;
        } else {
          int b = m >> 12, s = m & 4095;
          int h = e >> 6, d = e & 63;
          short* C = (short*)Cout;
          if (MODE == 2) {
            C[(size_t)((b * 8 + h) * 64 + d) * SEQ + s] = f2bf(val);
          } else {
            C[((size_t)(b * 8 + h) * SEQ + s) * 64 + d] = f2bf(val);
          }
        }
      }
    }
  }
}

// Flash attention, swapped QK^T, in-register softmax + P redistribution.
// grid = (SEQ/64, NBH), block 256 (4 waves x 16 q-rows).
// Qh pre-scaled by SCALE_Q (exp2 domain). Output ctx bf16 [B*S][512].
__global__ __launch_bounds__(256) void attn_kernel(
    const short* __restrict__ Qh, const short* __restrict__ Kh,
    const short* __restrict__ Vt, short* __restrict__ ctx)
{
  __shared__ short Ks[64][72];
  __shared__ short Vs[64][72];
  const int t    = threadIdx.x;
  const int lane = t & 63;
  const int w    = t >> 6;
  const int g    = lane >> 4;
  const int q    = lane & 15;
  const int bh   = blockIdx.y;
  const int q0   = blockIdx.x * 64 + w * 16;
  const size_t kvq   = (size_t)bh * SEQ * 64;
  const size_t vbase = (size_t)bh * 64 * SEQ;

  // Q as B-operand: B[n=q][k = kf*32 + g*8 + e]
  short8 qf[2];
#pragma unroll
  for (int kf = 0; kf < 2; ++kf)
    qf[kf] = *(const short8*)(Qh + kvq + (size_t)(q0 + q) * 64 + kf * 32 + g * 8);

  // ctx acc: D[m = 4g+j (q-row local)][n = 16*nb + q (dh)]
  f32x4 acc[4];
#pragma unroll
  for (int nb = 0; nb < 4; ++nb)
#pragma unroll
    for (int j = 0; j < 4; ++j) acc[nb][j] = 0.f;
  float mrun = -1e30f, lrun = 0.f;

  const int la = ((2 * g) & 3) * 16 + q;      // source lane for e 0..3
  const int lb = ((2 * g + 1) & 3) * 16 + q;  // source lane for e 4..7
  const bool hig = (g >= 2);                  // selects n = 2kf+1

  for (int kt = 0; kt < SEQ / 64; ++kt) {
    __syncthreads();
#pragma unroll
    for (int it = 0; it < 2; ++it) {
      int i = it * 256 + t;
      int r = i >> 3, sg = i & 7;
      *(i4v*)&Ks[r][sg * 8] = *(const i4v*)(Kh + kvq + (size_t)(kt * 64 + r) * 64 + sg * 8);
      *(i4v*)&Vs[r][sg * 8] = *(const i4v*)(Vt + vbase + (size_t)r * SEQ + kt * 64 + sg * 8);
    }
    __syncthreads();

    // S^T: sc[n][j] = S[k = 16n + 4g + j][q-row = q]   (exp2 domain)
    f32x4 sc[4];
#pragma unroll
    for (int n = 0; n < 4; ++n)
#pragma unroll
      for (int j = 0; j < 4; ++j) sc[n][j] = 0.f;
#pragma unroll
    for (int kf = 0; kf < 2; ++kf) {
#pragma unroll
      for (int n = 0; n < 4; ++n) {
        short8 kfr = *(const short8*)&Ks[n * 16 + q][kf * 32 + g * 8];
        sc[n] = __builtin_amdgcn_mfma_f32_16x16x32_bf16(kfr, qf[kf], sc[n], 0, 0, 0);
      }
    }

    // row max: 16 in-register values + reduce across groups (xor 16, 32)
    float pm = sc[0][0];
#pragma unroll
    for (int n = 0; n < 4; ++n)
#pragma unroll
      for (int j = 0; j < 4; ++j) pm = fmaxf(pm, sc[n][j]);
    pm = fmaxf(pm, __shfl_xor(pm, 16));
    pm = fmaxf(pm, __shfl_xor(pm, 32));

    const bool skip = __all(pm <= mrun + 11.0f);
    const float mnew = skip ? mrun : fmaxf(mrun, pm);

    float rs = 0.f;
#pragma unroll
    for (int n = 0; n < 4; ++n)
#pragma unroll
      for (int j = 0; j < 4; ++j) {
        float p = __builtin_amdgcn_exp2f(sc[n][j] - mnew);
        sc[n][j] = p;
        rs += p;
      }
    rs += __shfl_xor(rs, 16);
    rs += __shfl_xor(rs, 32);

    if (!skip) {
      float corr = __builtin_amdgcn_exp2f(mrun - mnew);
      lrun = lrun * corr + rs;
      mrun = mnew;
#pragma unroll
      for (int j = 0; j < 4; ++j) {
        float cj = __shfl(corr, 4 * g + j);
#pragma unroll
        for (int nb = 0; nb < 4; ++nb) acc[nb][j] *= cj;
      }
    } else {
      lrun += rs;
    }

    // pack P pairs: pk[n][h] = bf16x2(sc[n][2h], sc[n][2h+1])
    unsigned pk[4][2];
#pragma unroll
    for (int n = 0; n < 4; ++n)
#pragma unroll
      for (int h2 = 0; h2 < 2; ++h2)
        pk[n][h2] = cvt_pk_bf16(sc[n][2 * h2], sc[n][2 * h2 + 1]);

    // PV: A-frag lane needs P[q][k = kf*32 + 8g + e]
#pragma unroll
    for (int kf = 0; kf < 2; ++kf) {
      unsigned a0 = __shfl(pk[2 * kf + 0][0], la);
      unsigned a1 = __shfl(pk[2 * kf + 0][1], la);
      unsigned b0 = __shfl(pk[2 * kf + 1][0], la);
      unsigned b1 = __shfl(pk[2 * kf + 1][1], la);
      unsigned c0 = __shfl(pk[2 * kf + 0][0], lb);
      unsigned c1 = __shfl(pk[2 * kf + 0][1], lb);
      unsigned d0 = __shfl(pk[2 * kf + 1][0], lb);
      unsigned d1 = __shfl(pk[2 * kf + 1][1], lb);
      union { unsigned u[4]; short8 s8; } pf;
      pf.u[0] = hig ? b0 : a0;
      pf.u[1] = hig ? b1 : a1;
      pf.u[2] = hig ? d0 : c0;
      pf.u[3] = hig ? d1 : c1;
#pragma unroll
      for (int nb = 0; nb < 4; ++nb) {
        short8 vf = *(const short8*)&Vs[nb * 16 + q][kf * 32 + g * 8];
        acc[nb] = __builtin_amdgcn_mfma_f32_16x16x32_bf16(pf.s8, vf, acc[nb], 0, 0, 0);
      }
    }
  }

  const int b = bh >> 3, h = bh & 7;
  const float inv = 1.0f / lrun;
#pragma unroll
  for (int j = 0; j < 4; ++j) {
    float ij = __shfl(inv, 4 * g + j);
    int s = q0 + 4 * g + j;
    size_t row = (size_t)(b * SEQ + s);
#pragma unroll
    for (int nb = 0; nb < 4; ++nb) {
      int col = h * 64 + nb * 16 + q;
      ctx[row * 512 + col] = f2bf(acc[nb][j] * ij);
    }
  }
}

extern "C" void kernel_launch(void* const* d_in, const int* in_sizes, int n_in,
                              void* d_out, int out_size, void* d_ws, size_t ws_size,
                              hipStream_t stream) {
  const float* q  = (const float*)d_in[0];
  const float* k  = (const float*)d_in[1];
  const float* v  = (const float*)d_in[2];
  const float* Wq = (const float*)d_in[3];
  const float* bq = (const float*)d_in[4];
  const float* Wk = (const float*)d_in[5];
  const float* bk = (const float*)d_in[6];
  const float* Wv = (const float*)d_in[7];
  const float* bv = (const float*)d_in[8];
  const float* Wo = (const float*)d_in[9];
  const float* bo = (const float*)d_in[10];

  const size_t NELT = (size_t)NBH * SEQ * 64;  // 4,194,304
  short* Qh  = (short*)d_ws;
  short* Kh  = Qh + NELT;
  short* Vt  = Kh + NELT;
  short* ctx = Vt + NELT;

  dim3 gb(128, 4), tb(256);
  gemm_bt<0><<<gb, tb, 0, stream>>>(q, nullptr, Wq, bq, (void*)Qh);
  gemm_bt<1><<<gb, tb, 0, stream>>>(k, nullptr, Wk, bk, (void*)Kh);
  gemm_bt<2><<<gb, tb, 0, stream>>>(v, nullptr, Wv, bv, (void*)Vt);
  attn_kernel<<<dim3(SEQ / 64, NBH), tb, 0, stream>>>(Qh, Kh, Vt, ctx);
  gemm_bt<3><<<gb, tb, 0, stream>>>(nullptr, ctx, Wo, bo, d_out);
}

// Round 3
// 210.714 us; speedup vs baseline: 1.8173x; 1.1854x over previous
//
#include <hip/hip_runtime.h>
#include <hip/hip_bf16.h>

typedef __attribute__((ext_vector_type(8))) short short8;
typedef __attribute__((ext_vector_type(4))) float f32x4;
typedef __attribute__((ext_vector_type(16))) float f32x16;
typedef __attribute__((ext_vector_type(4))) float f4v;

#define SEQ 4096
#define NBH 16
// 1/sqrt(64) * log2(e): attention computed in exp2 domain
#define SCALE_Q 0.18033688011112042f

#define MFMA16(a, b, c) __builtin_amdgcn_mfma_f32_16x16x32_bf16(a, b, c, 0, 0, 0)
#define MFMA32(a, b, c) __builtin_amdgcn_mfma_f32_32x32x16_bf16(a, b, c, 0, 0, 0)

__device__ __forceinline__ short f2bf(float f) {
  union { float f; unsigned u; } x; x.f = f;
  unsigned r = x.u + 0x7FFFu + ((x.u >> 16) & 1u);
  return (short)(r >> 16);
}

__device__ __forceinline__ unsigned cvt_pk_bf16(float lo, float hi) {
  unsigned r;
  asm("v_cvt_pk_bf16_f32 %0, %1, %2" : "=v"(r) : "v"(lo), "v"(hi));
  return r;
}

__device__ __forceinline__ short8 cvt8(const float* __restrict__ src) {
  f4v v0 = *(const f4v*)src;
  f4v v1 = *(const f4v*)(src + 4);
  union { unsigned u[4]; short8 s; } r;
  r.u[0] = cvt_pk_bf16(v0[0], v0[1]);
  r.u[1] = cvt_pk_bf16(v0[2], v0[3]);
  r.u[2] = cvt_pk_bf16(v1[0], v1[1]);
  r.u[3] = cvt_pk_bf16(v1[2], v1[3]);
  return r.s;
}

__device__ __forceinline__ void gll16(const void* g, void* l) {
  __builtin_amdgcn_global_load_lds(
      (const __attribute__((address_space(1))) void*)g,
      (__attribute__((address_space(3))) void*)l, 16, 0, 0);
}

__device__ __forceinline__ void pswap(unsigned& a, unsigned& b) {
  asm volatile("v_permlane32_swap_b32 %0, %1" : "+v"(a), "+v"(b));
}

// ---------------- projection / output GEMMs ----------------
// C[M,N] = A[M,K] * W[N,K]^T + bias.  M=8192, N=K=512.
// grid = (4 n-tiles, 128 m-tiles). BM=64, BN=128, BK=64, 4 waves.
// MODE 0: A fp32 (q) -> Qh bf16 [BH][SEQ][64], scaled by SCALE_Q
// MODE 1: A fp32 (k) -> Kh bf16 [BH][SEQ][64]
// MODE 2: A fp32 (v) -> Vt bf16 [BH][64][SEQ]  (operand-swapped mfma -> direct
//         transposed store, contiguous along s)
// MODE 3: A bf16 (ctx) -> out fp32 [M][512]
template <int MODE>
__global__ __launch_bounds__(256) void gemm_bt(
    const float* __restrict__ Af, const short* __restrict__ Ab,
    const float* __restrict__ W, const float* __restrict__ bias,
    void* __restrict__ Cout)
{
  __shared__ short As[64][72];
  __shared__ short Bs[128][72];
  const int t    = threadIdx.x;
  const int lane = t & 63;
  const int w    = t >> 6;
  const int g    = lane >> 4;
  const int q    = lane & 15;
  const int tile_n = blockIdx.x * 128;
  const int tile_m = blockIdx.y * 64;

  f32x4 acc[4][2];
#pragma unroll
  for (int mi = 0; mi < 4; ++mi)
#pragma unroll
    for (int ni = 0; ni < 2; ++ni)
#pragma unroll
      for (int j = 0; j < 4; ++j) acc[mi][ni][j] = 0.f;

  for (int k0 = 0; k0 < 512; k0 += 64) {
    __syncthreads();
    if (MODE != 3) {
#pragma unroll
      for (int it = 0; it < 2; ++it) {
        int i = it * 256 + t;
        int r = i >> 3, sg = i & 7;
        *(short8*)&As[r][sg * 8] =
            cvt8(Af + (size_t)(tile_m + r) * 512 + k0 + sg * 8);
      }
    } else {
#pragma unroll
      for (int it = 0; it < 2; ++it) {
        int i = it * 256 + t;
        int r = i >> 3, sg = i & 7;
        *(short8*)&As[r][sg * 8] =
            *(const short8*)(Ab + (size_t)(tile_m + r) * 512 + k0 + sg * 8);
      }
    }
#pragma unroll
    for (int it = 0; it < 4; ++it) {
      int i = it * 256 + t;
      int r = i >> 3, sg = i & 7;
      *(short8*)&Bs[r][sg * 8] =
          cvt8(W + (size_t)(tile_n + r) * 512 + k0 + sg * 8);
    }
    __syncthreads();
#pragma unroll
    for (int kk = 0; kk < 2; ++kk) {
      short8 af[4], bfv[2];
#pragma unroll
      for (int mi = 0; mi < 4; ++mi)
        af[mi] = *(const short8*)&As[mi * 16 + q][kk * 32 + g * 8];
#pragma unroll
      for (int ni = 0; ni < 2; ++ni)
        bfv[ni] = *(const short8*)&Bs[w * 32 + ni * 16 + q][kk * 32 + g * 8];
#pragma unroll
      for (int mi = 0; mi < 4; ++mi)
#pragma unroll
        for (int ni = 0; ni < 2; ++ni) {
          if (MODE == 2)
            acc[mi][ni] = MFMA16(bfv[ni], af[mi], acc[mi][ni]);
          else
            acc[mi][ni] = MFMA16(af[mi], bfv[ni], acc[mi][ni]);
        }
    }
  }

#pragma unroll
  for (int mi = 0; mi < 4; ++mi) {
#pragma unroll
    for (int ni = 0; ni < 2; ++ni) {
#pragma unroll
      for (int j = 0; j < 4; ++j) {
        if (MODE == 2) {
          // D[m = e][n = s]
          int e = tile_n + w * 32 + ni * 16 + 4 * g + j;
          int srow = tile_m + mi * 16 + q;
          float val = acc[mi][ni][j] + bias[e];
          int b = srow >> 12, sl = srow & 4095;
          int h = e >> 6, d = e & 63;
          ((short*)Cout)[((size_t)((b * 8 + h) * 64 + d)) * SEQ + sl] = f2bf(val);
        } else {
          int m = tile_m + mi * 16 + g * 4 + j;
          int e = tile_n + w * 32 + ni * 16 + q;
          float val = acc[mi][ni][j] + bias[e];
          if (MODE == 0) val *= SCALE_Q;
          if (MODE == 3) {
            ((float*)Cout)[(size_t)m * 512 + e] = val;
          } else {
            int b = m >> 12, s = m & 4095;
            int h = e >> 6, d = e & 63;
            ((short*)Cout)[((size_t)(b * 8 + h) * SEQ + s) * 64 + d] = f2bf(val);
          }
        }
      }
    }
  }
}

// ---------------- flash attention, 32x32 MFMA ----------------
// grid = 512 blocks (XCD-swizzled -> 32 q-tiles x 16 bh), block 256 = 4 waves,
// each wave owns 32 q-rows. KV tile = 64 tokens, double-buffered in LDS via
// global_load_lds with XOR-swizzled source. Qh pre-scaled (exp2 domain).
__global__ __launch_bounds__(256) void attn_kernel(
    const short* __restrict__ Qh, const short* __restrict__ Kh,
    const short* __restrict__ Vt, short* __restrict__ ctx)
{
  __shared__ __align__(16) char smem[2][16384];  // [buf][K 8KB | V 8KB]
  const int t    = threadIdx.x;
  const int lane = t & 63;
  const int w    = t >> 6;
  const int l31  = lane & 31;
  const int hi   = lane >> 5;

  // XCD-aware swizzle: 64 consecutive logical blocks (2 bh) per XCD
  const int fid = blockIdx.x;
  const int lid = (fid & 7) * 64 + (fid >> 3);
  const int qt  = lid & 31;
  const int bh  = lid >> 5;

  const size_t kbase = (size_t)bh * SEQ * 64;
  const size_t vbase = (size_t)bh * 64 * SEQ;
  const int q0 = qt * 128 + w * 32;

  // Q fragments (B-operand): lane: n = l31 (q-row), k = hi*8 + e, per dh-window m
  short8 qf[4];
#pragma unroll
  for (int m = 0; m < 4; ++m)
    qf[m] = *(const short8*)(Qh + kbase + (size_t)(q0 + l31) * 64 + m * 16 + hi * 8);

  f32x16 acc0, acc1;
#pragma unroll
  for (int r = 0; r < 16; ++r) { acc0[r] = 0.f; acc1[r] = 0.f; }
  float mrun = -1e30f, lrun = 0.f;

  // staging: wave w stages chunks w*4+i (c<8: K rows 8c.., c>=8: V rows 8(c-8)..)
  const int rif  = lane >> 3;                   // row within 8-row chunk
  const int scol = ((lane & 7) ^ rif) * 16;     // pre-swizzled source byte col
  // read-side xor (byte): includes the hi*16 k-group offset
  const int xr = (hi * 16) ^ ((lane & 7) << 4);

#define STAGE(buf, kt)                                                         \
  {                                                                            \
    _Pragma("unroll")                                                          \
    for (int i = 0; i < 4; ++i) {                                              \
      int c = w * 4 + i;                                                       \
      char* ldst = &smem[buf][c * 1024];                                       \
      if (c < 8) {                                                             \
        int row = c * 8 + rif;                                                 \
        const char* gp = (const char*)Kh +                                     \
            ((kbase + (size_t)((kt) * 64 + row) * 64) * 2 + scol);             \
        gll16(gp, ldst);                                                       \
      } else {                                                                 \
        int row = (c - 8) * 8 + rif;                                           \
        const char* gp = (const char*)Vt +                                     \
            ((vbase + (size_t)row * SEQ + (kt) * 64) * 2 + scol);              \
        gll16(gp, ldst);                                                       \
      }                                                                        \
    }                                                                          \
  }

  STAGE(0, 0);
  int cur = 0;

  for (int kt = 0; kt < SEQ / 64; ++kt) {
    if (kt < SEQ / 64 - 1) {
      STAGE(cur ^ 1, kt + 1);
      asm volatile("s_waitcnt vmcnt(4)" ::: "memory");
    } else {
      asm volatile("s_waitcnt vmcnt(0)" ::: "memory");
    }
    __builtin_amdgcn_sched_barrier(0);
    __builtin_amdgcn_s_barrier();
    __builtin_amdgcn_sched_barrier(0);

    const char* Kb = &smem[cur][0];
    const char* Vb = &smem[cur][8192];

    // QK^T for both 32-key chunks (swapped: A=K, B=Q -> D[key][q])
    f32x16 s0, s1;
#pragma unroll
    for (int r = 0; r < 16; ++r) { s0[r] = 0.f; s1[r] = 0.f; }
#pragma unroll
    for (int m = 0; m < 4; ++m) {
      short8 k0 = *(const short8*)(Kb + (size_t)(l31) * 128 + ((32 * m) ^ xr));
      short8 k1 = *(const short8*)(Kb + (size_t)(32 + l31) * 128 + ((32 * m) ^ xr));
      s0 = MFMA32(k0, qf[m], s0);
      s1 = MFMA32(k1, qf[m], s1);
    }

    // per-chunk online softmax + PV
#pragma unroll
    for (int c = 0; c < 2; ++c) {
      f32x16& s = c ? s1 : s0;

      float red[16];
#pragma unroll
      for (int r = 0; r < 16; ++r) red[r] = s[r];
#pragma unroll
      for (int st = 8; st >= 1; st >>= 1)
#pragma unroll
        for (int r = 0; r < st; ++r) red[r] = fmaxf(red[r], red[r + st]);
      float pm = red[0];
      pm = fmaxf(pm, __shfl_xor(pm, 32));

      const bool skip = __all(pm <= mrun + 11.0f);
      const float mnew = skip ? mrun : fmaxf(mrun, pm);

#pragma unroll
      for (int r = 0; r < 16; ++r) s[r] = __builtin_amdgcn_exp2f(s[r] - mnew);

#pragma unroll
      for (int r = 0; r < 16; ++r) red[r] = s[r];
#pragma unroll
      for (int st = 8; st >= 1; st >>= 1)
#pragma unroll
        for (int r = 0; r < st; ++r) red[r] += red[r + st];
      float rs = red[0];
      rs += __shfl_xor(rs, 32);

      if (!skip) {
        float corr = __builtin_amdgcn_exp2f(mrun - mnew);
        lrun = lrun * corr + rs;
        mrun = mnew;
#pragma unroll
        for (int r = 0; r < 16; ++r) {
          float cr = __shfl(corr, ((r & 3) + 8 * (r >> 2)) + 4 * hi);
          acc0[r] *= cr;
          acc1[r] *= cr;
        }
      } else {
        lrun += rs;
      }

      // pack P to bf16 pairs; pk[p] holds keys (8*(p>>1) + 4*hi + 2*(p&1) + {0,1})
      unsigned pk0 = cvt_pk_bf16(s[0], s[1]);
      unsigned pk1 = cvt_pk_bf16(s[2], s[3]);
      unsigned pk2 = cvt_pk_bf16(s[4], s[5]);
      unsigned pk3 = cvt_pk_bf16(s[6], s[7]);
      unsigned pk4 = cvt_pk_bf16(s[8], s[9]);
      unsigned pk5 = cvt_pk_bf16(s[10], s[11]);
      unsigned pk6 = cvt_pk_bf16(s[12], s[13]);
      unsigned pk7 = cvt_pk_bf16(s[14], s[15]);
      // redistribute into PV A-fragments (keys 0..15 -> A0, 16..31 -> A1)
      pswap(pk0, pk2);
      pswap(pk1, pk3);
      pswap(pk4, pk6);
      pswap(pk5, pk7);
      union { unsigned u[4]; short8 v; } A0, A1;
      A0.u[0] = pk0; A0.u[1] = pk1; A0.u[2] = pk2; A0.u[3] = pk3;
      A1.u[0] = pk4; A1.u[1] = pk5; A1.u[2] = pk6; A1.u[3] = pk7;

#pragma unroll
      for (int h2 = 0; h2 < 2; ++h2) {
        short8 pa = h2 ? A1.v : A0.v;
        short8 vf0 = *(const short8*)(Vb + (size_t)(l31) * 128 +
                                      ((64 * c + 32 * h2) ^ xr));
        short8 vf1 = *(const short8*)(Vb + (size_t)(32 + l31) * 128 +
                                      ((64 * c + 32 * h2) ^ xr));
        acc0 = MFMA32(pa, vf0, acc0);
        acc1 = MFMA32(pa, vf1, acc1);
      }
    }

    __builtin_amdgcn_sched_barrier(0);
    __builtin_amdgcn_s_barrier();
    __builtin_amdgcn_sched_barrier(0);
    cur ^= 1;
  }

  const int b = bh >> 3, hh = bh & 7;
  const float inv = 1.0f / lrun;
#pragma unroll
  for (int r = 0; r < 16; ++r) {
    int ql = (r & 3) + 8 * (r >> 2) + 4 * hi;
    float iv = __shfl(inv, ql);
    int qrow = q0 + ql;
    size_t off = ((size_t)(b * SEQ + qrow)) * 512 + hh * 64 + l31;
    ctx[off]      = f2bf(acc0[r] * iv);
    ctx[off + 32] = f2bf(acc1[r] * iv);
  }
}

extern "C" void kernel_launch(void* const* d_in, const int* in_sizes, int n_in,
                              void* d_out, int out_size, void* d_ws, size_t ws_size,
                              hipStream_t stream) {
  const float* q  = (const float*)d_in[0];
  const float* k  = (const float*)d_in[1];
  const float* v  = (const float*)d_in[2];
  const float* Wq = (const float*)d_in[3];
  const float* bq = (const float*)d_in[4];
  const float* Wk = (const float*)d_in[5];
  const float* bk = (const float*)d_in[6];
  const float* Wv = (const float*)d_in[7];
  const float* bv = (const float*)d_in[8];
  const float* Wo = (const float*)d_in[9];
  const float* bo = (const float*)d_in[10];

  const size_t NELT = (size_t)NBH * SEQ * 64;
  short* Qh  = (short*)d_ws;
  short* Kh  = Qh + NELT;
  short* Vt  = Kh + NELT;
  short* ctx = Vt + NELT;

  dim3 gb(4, 128), tb(256);
  gemm_bt<0><<<gb, tb, 0, stream>>>(q, nullptr, Wq, bq, (void*)Qh);
  gemm_bt<1><<<gb, tb, 0, stream>>>(k, nullptr, Wk, bk, (void*)Kh);
  gemm_bt<2><<<gb, tb, 0, stream>>>(v, nullptr, Wv, bv, (void*)Vt);
  attn_kernel<<<dim3(512), tb, 0, stream>>>(Qh, Kh, Vt, ctx);
  gemm_bt<3><<<gb, tb, 0, stream>>>(nullptr, ctx, Wo, bo, d_out);
}

// Round 4
// 171.724 us; speedup vs baseline: 2.2299x; 1.2270x over previous
//
#include <hip/hip_runtime.h>
#include <hip/hip_bf16.h>

typedef __attribute__((ext_vector_type(8))) short short8;
typedef __attribute__((ext_vector_type(4))) float f32x4;
typedef __attribute__((ext_vector_type(16))) float f32x16;
typedef __attribute__((ext_vector_type(4))) float f4v;

#define SEQ 4096
#define NBH 16
// 1/sqrt(64) * log2(e): attention computed in exp2 domain
#define SCALE_Q 0.18033688011112042f

#define MFMA16(a, b, c) __builtin_amdgcn_mfma_f32_16x16x32_bf16(a, b, c, 0, 0, 0)
#define MFMA32(a, b, c) __builtin_amdgcn_mfma_f32_32x32x16_bf16(a, b, c, 0, 0, 0)

__device__ __forceinline__ short f2bf(float f) {
  union { float f; unsigned u; } x; x.f = f;
  unsigned r = x.u + 0x7FFFu + ((x.u >> 16) & 1u);
  return (short)(r >> 16);
}

__device__ __forceinline__ unsigned cvt_pk_bf16(float lo, float hi) {
  unsigned r;
  asm("v_cvt_pk_bf16_f32 %0, %1, %2" : "=v"(r) : "v"(lo), "v"(hi));
  return r;
}

__device__ __forceinline__ short8 cvt8(const float* __restrict__ src) {
  f4v v0 = *(const f4v*)src;
  f4v v1 = *(const f4v*)(src + 4);
  union { unsigned u[4]; short8 s; } r;
  r.u[0] = cvt_pk_bf16(v0[0], v0[1]);
  r.u[1] = cvt_pk_bf16(v0[2], v0[3]);
  r.u[2] = cvt_pk_bf16(v1[0], v1[1]);
  r.u[3] = cvt_pk_bf16(v1[2], v1[3]);
  return r.s;
}

__device__ __forceinline__ void gll16(const void* g, void* l) {
  __builtin_amdgcn_global_load_lds(
      (const __attribute__((address_space(1))) void*)g,
      (__attribute__((address_space(3))) void*)l, 16, 0, 0);
}

__device__ __forceinline__ void pswap(unsigned& a, unsigned& b) {
  asm volatile("v_permlane32_swap_b32 %0, %1" : "+v"(a), "+v"(b));
}

// ---------------- fp32 -> bf16 weight pre-convert ----------------
// 4 x 512x512 matrices -> Wb (bf16, concatenated). 8 elems/thread.
__global__ __launch_bounds__(256) void cvt_w(
    const float* __restrict__ w0, const float* __restrict__ w1,
    const float* __restrict__ w2, const float* __restrict__ w3,
    short* __restrict__ dst)
{
  int i = blockIdx.x * 256 + threadIdx.x;   // chunk of 8, 32768 per matrix
  int m = i >> 15;
  int off = (i & 32767) * 8;
  const float* s = (m == 0) ? w0 : (m == 1) ? w1 : (m == 2) ? w2 : w3;
  *(short8*)(dst + (size_t)m * 262144 + off) = cvt8(s + off);
}

// ---------------- projection / output GEMMs ----------------
// C[M,N] = A[M,K] * Wb[N,K]^T + bias.  M=8192, N=K=512. Wb bf16.
// grid = (4 n-tiles, 128 m-tiles). BM=64, BN=128, BK=64, 4 waves.
// B staged via global_load_lds into XOR-swizzled linear LDS.
// MODE 0: A fp32 (q) -> Qh bf16 [BH][SEQ][64], scaled by SCALE_Q
// MODE 1: A fp32 (k) -> Kh bf16 [BH][SEQ][64]
// MODE 2: A fp32 (v) -> Vt bf16 [BH][64][SEQ] (operand-swapped mfma)
// MODE 3: A bf16 (ctx) -> out fp32 [M][512]; A also gll-staged.
template <int MODE>
__global__ __launch_bounds__(256) void gemm_bt(
    const float* __restrict__ Af, const short* __restrict__ Ab,
    const short* __restrict__ Wb, const float* __restrict__ bias,
    void* __restrict__ Cout)
{
  __shared__ __align__(16) char smemA[64 * 72 * 2];   // padded (MODE<3) or linear 8KB (MODE3)
  __shared__ __align__(16) char smemB[128 * 64 * 2];  // linear swizzled
  short (*As)[72] = (short(*)[72])smemA;
  const int t    = threadIdx.x;
  const int lane = t & 63;
  const int w    = t >> 6;
  const int g    = lane >> 4;
  const int q    = lane & 15;
  const int tile_n = blockIdx.x * 128;
  const int tile_m = blockIdx.y * 64;

  f32x4 acc[4][2];
#pragma unroll
  for (int mi = 0; mi < 4; ++mi)
#pragma unroll
    for (int ni = 0; ni < 2; ++ni)
#pragma unroll
      for (int j = 0; j < 4; ++j) acc[mi][ni][j] = 0.f;

  for (int k0 = 0; k0 < 512; k0 += 64) {
    __syncthreads();
    // ---- stage A ----
    if (MODE != 3) {
#pragma unroll
      for (int it = 0; it < 2; ++it) {
        int i = it * 256 + t;
        int r = i >> 3, sg = i & 7;
        *(short8*)&As[r][sg * 8] =
            cvt8(Af + (size_t)(tile_m + r) * 512 + k0 + sg * 8);
      }
    } else {
#pragma unroll
      for (int it = 0; it < 2; ++it) {
        int i = it * 256 + t;
        int row = i >> 3, cg = i & 7;
        const char* gp = (const char*)Ab +
            ((size_t)(tile_m + row) * 512 + k0) * 2 + ((cg ^ (row & 7)) << 4);
        gll16(gp, smemA + (size_t)(it * 256 + (t & ~63)) * 16);
      }
    }
    // ---- stage B via gll, swizzled source ----
#pragma unroll
    for (int it = 0; it < 4; ++it) {
      int i = it * 256 + t;
      int row = i >> 3, cg = i & 7;
      const char* gp = (const char*)Wb +
          ((size_t)(tile_n + row) * 512 + k0) * 2 + ((cg ^ (row & 7)) << 4);
      gll16(gp, smemB + (size_t)(it * 256 + (t & ~63)) * 16);
    }
    __syncthreads();
#pragma unroll
    for (int kk = 0; kk < 2; ++kk) {
      short8 af[4], bfv[2];
#pragma unroll
      for (int mi = 0; mi < 4; ++mi) {
        int rA = mi * 16 + q;
        if (MODE != 3)
          af[mi] = *(const short8*)&As[rA][kk * 32 + g * 8];
        else
          af[mi] = *(const short8*)(smemA + rA * 128 +
                                    (((4 * kk + g) ^ (rA & 7)) << 4));
      }
#pragma unroll
      for (int ni = 0; ni < 2; ++ni) {
        int rB = w * 32 + ni * 16 + q;
        bfv[ni] = *(const short8*)(smemB + rB * 128 +
                                   (((4 * kk + g) ^ (rB & 7)) << 4));
      }
#pragma unroll
      for (int mi = 0; mi < 4; ++mi)
#pragma unroll
        for (int ni = 0; ni < 2; ++ni) {
          if (MODE == 2)
            acc[mi][ni] = MFMA16(bfv[ni], af[mi], acc[mi][ni]);
          else
            acc[mi][ni] = MFMA16(af[mi], bfv[ni], acc[mi][ni]);
        }
    }
  }

#pragma unroll
  for (int mi = 0; mi < 4; ++mi) {
#pragma unroll
    for (int ni = 0; ni < 2; ++ni) {
#pragma unroll
      for (int j = 0; j < 4; ++j) {
        if (MODE == 2) {
          int e = tile_n + w * 32 + ni * 16 + 4 * g + j;
          int srow = tile_m + mi * 16 + q;
          float val = acc[mi][ni][j] + bias[e];
          int b = srow >> 12, sl = srow & 4095;
          int h = e >> 6, d = e & 63;
          ((short*)Cout)[((size_t)((b * 8 + h) * 64 + d)) * SEQ + sl] = f2bf(val);
        } else {
          int m = tile_m + mi * 16 + g * 4 + j;
          int e = tile_n + w * 32 + ni * 16 + q;
          float val = acc[mi][ni][j] + bias[e];
          if (MODE == 0) val *= SCALE_Q;
          if (MODE == 3) {
            ((float*)Cout)[(size_t)m * 512 + e] = val;
          } else {
            int b = m >> 12, s = m & 4095;
            int h = e >> 6, d = e & 63;
            ((short*)Cout)[((size_t)(b * 8 + h) * SEQ + s) * 64 + d] = f2bf(val);
          }
        }
      }
    }
  }
}

// ---------------- flash attention, 32x32 MFMA ----------------
// grid = 512 (XCD-swizzled), 4 waves x 32 q-rows. KV tile = 64 tokens,
// double-buffered via global_load_lds (swizzled source). exp2 domain.
__global__ __launch_bounds__(256) void attn_kernel(
    const short* __restrict__ Qh, const short* __restrict__ Kh,
    const short* __restrict__ Vt, short* __restrict__ ctx)
{
  __shared__ __align__(16) char smem[2][16384];  // [buf][K 8KB | V 8KB]
  const int t    = threadIdx.x;
  const int lane = t & 63;
  const int w    = t >> 6;
  const int l31  = lane & 31;
  const int hi   = lane >> 5;

  const int fid = blockIdx.x;
  const int lid = (fid & 7) * 64 + (fid >> 3);
  const int qt  = lid & 31;
  const int bh  = lid >> 5;

  const size_t kbase = (size_t)bh * SEQ * 64;
  const size_t vbase = (size_t)bh * 64 * SEQ;
  const int q0 = qt * 128 + w * 32;

  short8 qf[4];
#pragma unroll
  for (int m = 0; m < 4; ++m)
    qf[m] = *(const short8*)(Qh + kbase + (size_t)(q0 + l31) * 64 + m * 16 + hi * 8);

  f32x16 fz;
#pragma unroll
  for (int r = 0; r < 16; ++r) fz[r] = 0.f;
  f32x16 acc0 = fz, acc1 = fz;
  float mrun = -1e30f, lrun = 0.f;

  const int rif  = lane >> 3;
  const int scol = ((lane & 7) ^ rif) * 16;
  const int xr   = (hi * 16) ^ ((lane & 7) << 4);

#define STAGE(buf, kt)                                                         \
  {                                                                            \
    _Pragma("unroll")                                                          \
    for (int i = 0; i < 4; ++i) {                                              \
      int c = w * 4 + i;                                                       \
      char* ldst = &smem[buf][c * 1024];                                       \
      if (c < 8) {                                                             \
        int row = c * 8 + rif;                                                 \
        const char* gp = (const char*)Kh +                                     \
            ((kbase + (size_t)((kt) * 64 + row) * 64) * 2 + scol);             \
        gll16(gp, ldst);                                                       \
      } else {                                                                 \
        int row = (c - 8) * 8 + rif;                                           \
        const char* gp = (const char*)Vt +                                     \
            ((vbase + (size_t)row * SEQ + (kt) * 64) * 2 + scol);              \
        gll16(gp, ldst);                                                       \
      }                                                                        \
    }                                                                          \
  }

  STAGE(0, 0);
  int cur = 0;

  for (int kt = 0; kt < SEQ / 64; ++kt) {
    if (kt < SEQ / 64 - 1) {
      STAGE(cur ^ 1, kt + 1);
      asm volatile("s_waitcnt vmcnt(4)" ::: "memory");
    } else {
      asm volatile("s_waitcnt vmcnt(0)" ::: "memory");
    }
    __builtin_amdgcn_sched_barrier(0);
    __builtin_amdgcn_s_barrier();
    __builtin_amdgcn_sched_barrier(0);

    const char* Kb = &smem[cur][0];
    const char* Vb = &smem[cur][8192];

    // QK^T (swapped: A=K, B=Q -> D[key][q]), C starts from zero vector
    f32x16 s0, s1;
    {
      short8 k0 = *(const short8*)(Kb + (size_t)(l31) * 128 + ((32 * 0) ^ xr));
      short8 k1 = *(const short8*)(Kb + (size_t)(32 + l31) * 128 + ((32 * 0) ^ xr));
      __builtin_amdgcn_s_setprio(1);
      s0 = MFMA32(k0, qf[0], fz);
      s1 = MFMA32(k1, qf[0], fz);
      __builtin_amdgcn_s_setprio(0);
    }
#pragma unroll
    for (int m = 1; m < 4; ++m) {
      short8 k0 = *(const short8*)(Kb + (size_t)(l31) * 128 + ((32 * m) ^ xr));
      short8 k1 = *(const short8*)(Kb + (size_t)(32 + l31) * 128 + ((32 * m) ^ xr));
      __builtin_amdgcn_s_setprio(1);
      s0 = MFMA32(k0, qf[m], s0);
      s1 = MFMA32(k1, qf[m], s1);
      __builtin_amdgcn_s_setprio(0);
    }

    // ---- merged online softmax over all 64 keys ----
    float a_[16];
#pragma unroll
    for (int r = 0; r < 16; ++r) a_[r] = fmaxf(s0[r], s1[r]);
#pragma unroll
    for (int r = 0; r < 8; ++r) a_[r] = fmaxf(a_[r], a_[r + 8]);
#pragma unroll
    for (int r = 0; r < 4; ++r) a_[r] = fmaxf(a_[r], a_[r + 4]);
    float pm = fmaxf(fmaxf(a_[0], a_[1]), fmaxf(a_[2], a_[3]));
    pm = fmaxf(pm, __shfl_xor(pm, 32));

    const bool skip = __all(pm <= mrun + 11.0f);
    const float mnew = skip ? mrun : fmaxf(mrun, pm);

#pragma unroll
    for (int r = 0; r < 16; ++r) {
      s0[r] = __builtin_amdgcn_exp2f(s0[r] - mnew);
      s1[r] = __builtin_amdgcn_exp2f(s1[r] - mnew);
    }

    float b_[16];
#pragma unroll
    for (int r = 0; r < 16; ++r) b_[r] = s0[r] + s1[r];
#pragma unroll
    for (int r = 0; r < 8; ++r) b_[r] += b_[r + 8];
#pragma unroll
    for (int r = 0; r < 4; ++r) b_[r] += b_[r + 4];
    float rs = (b_[0] + b_[1]) + (b_[2] + b_[3]);
    rs += __shfl_xor(rs, 32);

    if (!skip) {
      float corr = __builtin_amdgcn_exp2f(mrun - mnew);
      lrun = lrun * corr + rs;
      mrun = mnew;
#pragma unroll
      for (int r = 0; r < 16; ++r) {
        float cr = __shfl(corr, ((r & 3) + 8 * (r >> 2)) + 4 * hi);
        acc0[r] *= cr;
        acc1[r] *= cr;
      }
    } else {
      lrun += rs;
    }

    // ---- pack P for both chunks, then PV ----
    union { unsigned u[4]; short8 v; } A0[2], A1[2];
#pragma unroll
    for (int c = 0; c < 2; ++c) {
      const f32x16& s = c ? s1 : s0;
      unsigned pk0 = cvt_pk_bf16(s[0], s[1]);
      unsigned pk1 = cvt_pk_bf16(s[2], s[3]);
      unsigned pk2 = cvt_pk_bf16(s[4], s[5]);
      unsigned pk3 = cvt_pk_bf16(s[6], s[7]);
      unsigned pk4 = cvt_pk_bf16(s[8], s[9]);
      unsigned pk5 = cvt_pk_bf16(s[10], s[11]);
      unsigned pk6 = cvt_pk_bf16(s[12], s[13]);
      unsigned pk7 = cvt_pk_bf16(s[14], s[15]);
      pswap(pk0, pk2);
      pswap(pk1, pk3);
      pswap(pk4, pk6);
      pswap(pk5, pk7);
      A0[c].u[0] = pk0; A0[c].u[1] = pk1; A0[c].u[2] = pk2; A0[c].u[3] = pk3;
      A1[c].u[0] = pk4; A1[c].u[1] = pk5; A1[c].u[2] = pk6; A1[c].u[3] = pk7;
    }

#pragma unroll
    for (int c = 0; c < 2; ++c) {
#pragma unroll
      for (int h2 = 0; h2 < 2; ++h2) {
        short8 pa = h2 ? A1[c].v : A0[c].v;
        short8 vf0 = *(const short8*)(Vb + (size_t)(l31) * 128 +
                                      ((64 * c + 32 * h2) ^ xr));
        short8 vf1 = *(const short8*)(Vb + (size_t)(32 + l31) * 128 +
                                      ((64 * c + 32 * h2) ^ xr));
        __builtin_amdgcn_s_setprio(1);
        acc0 = MFMA32(pa, vf0, acc0);
        acc1 = MFMA32(pa, vf1, acc1);
        __builtin_amdgcn_s_setprio(0);
      }
    }

    __builtin_amdgcn_sched_barrier(0);
    __builtin_amdgcn_s_barrier();
    __builtin_amdgcn_sched_barrier(0);
    cur ^= 1;
  }

  const int b = bh >> 3, hh = bh & 7;
  const float inv = 1.0f / lrun;
#pragma unroll
  for (int r = 0; r < 16; ++r) {
    int ql = (r & 3) + 8 * (r >> 2) + 4 * hi;
    float iv = __shfl(inv, ql);
    int qrow = q0 + ql;
    size_t off = ((size_t)(b * SEQ + qrow)) * 512 + hh * 64 + l31;
    ctx[off]      = f2bf(acc0[r] * iv);
    ctx[off + 32] = f2bf(acc1[r] * iv);
  }
}

extern "C" void kernel_launch(void* const* d_in, const int* in_sizes, int n_in,
                              void* d_out, int out_size, void* d_ws, size_t ws_size,
                              hipStream_t stream) {
  const float* q  = (const float*)d_in[0];
  const float* k  = (const float*)d_in[1];
  const float* v  = (const float*)d_in[2];
  const float* Wq = (const float*)d_in[3];
  const float* bq = (const float*)d_in[4];
  const float* Wk = (const float*)d_in[5];
  const float* bk = (const float*)d_in[6];
  const float* Wv = (const float*)d_in[7];
  const float* bv = (const float*)d_in[8];
  const float* Wo = (const float*)d_in[9];
  const float* bo = (const float*)d_in[10];

  const size_t NELT = (size_t)NBH * SEQ * 64;  // 4,194,304
  short* Qh  = (short*)d_ws;
  short* Kh  = Qh + NELT;
  short* Vt  = Kh + NELT;
  short* ctx = Vt + NELT;
  short* Wb  = ctx + NELT;   // 4 x 262144 bf16

  dim3 tb(256);
  cvt_w<<<dim3(512), tb, 0, stream>>>(Wq, Wk, Wv, Wo, Wb);

  dim3 gb(4, 128);
  gemm_bt<0><<<gb, tb, 0, stream>>>(q, nullptr, Wb,          bq, (void*)Qh);
  gemm_bt<1><<<gb, tb, 0, stream>>>(k, nullptr, Wb + 262144, bk, (void*)Kh);
  gemm_bt<2><<<gb, tb, 0, stream>>>(v, nullptr, Wb + 524288, bv, (void*)Vt);
  attn_kernel<<<dim3(512), tb, 0, stream>>>(Qh, Kh, Vt, ctx);
  gemm_bt<3><<<gb, tb, 0, stream>>>(nullptr, ctx, Wb + 786432, bo, d_out);
}